// Round 7
// baseline (280.839 us; speedup 1.0000x reference)
//
#include <hip/hip_runtime.h>
#include <stdint.h>

constexpr int N_CLASSES = 1000;
constexpr int EMBED     = 1024;   // 256 float4 per row; 4 float4 per lane
constexpr int ROWS_PER_BLOCK = 8; // 4 waves x 2 rows
constexpr int LAB_BYTES = N_CLASSES * 4;   // 4000, divisible by 16

typedef float floatx4 __attribute__((ext_vector_type(4)));

// Async global->LDS, 16B per lane, no VGPR landing (m97 path).
// LDS dest is wave-uniform base + lane*16; gptr is per-lane.
__device__ __forceinline__ void gl2lds16(const void* g, void* l) {
    __builtin_amdgcn_global_load_lds(
        (const __attribute__((address_space(1))) void*)g,
        (__attribute__((address_space(3))) void*)l,
        16, 0, 0);
}

// Block owns 8 rows; wave w owns rows 2w, 2w+1 (wave-private, one barrier).
//  - labels: async-staged to LDS (escapes the VGPR landing-register cap)
//  - features: plain cached float4 loads into VGPRs (issued before barrier)
//  - protos: cached gather after ballot
__global__ __launch_bounds__(256) void angular_fused_kernel(
    const float* __restrict__ features,
    const float* __restrict__ labels,
    const float* __restrict__ mean_class,
    float* __restrict__ partials,
    int n_rows)
{
    const int tid  = threadIdx.x;
    const int lane = tid & 63;
    const int wave = tid >> 6;
    const int row0 = blockIdx.x * ROWS_PER_BLOCK;

    __shared__ __align__(16) char s_lab[ROWS_PER_BLOCK][LAB_BYTES];
    __shared__ float s_red[4];

    const int rA = row0 + 2 * wave;
    const int rB = rA + 1;
    const bool okA = rA < n_rows, okB = rB < n_rows;
    const int rAc = okA ? rA : 0;     // clamp for safe (duplicated) work
    const int rBc = okB ? rB : 0;

    // ---- async-stage this wave's two label rows into LDS ----
    {
        const char* gA = (const char*)labels + (size_t)rAc * LAB_BYTES;
        const char* gB = (const char*)labels + (size_t)rBc * LAB_BYTES;
        char* lA = &s_lab[2 * wave][0];
        char* lB = &s_lab[2 * wave + 1][0];
        #pragma unroll
        for (int c = 0; c < 3; ++c) {               // 3 x 1024 B per row
            gl2lds16(gA + c * 1024 + lane * 16, lA + c * 1024);
            gl2lds16(gB + c * 1024 + lane * 16, lB + c * 1024);
        }
        if (lane < 58) {                            // tail 928 B (3072..4000)
            gl2lds16(gA + 3072 + lane * 16, lA + 3072);
            gl2lds16(gB + 3072 + lane * 16, lB + 3072);
        }
    }

    // ---- feature loads for both rows (plain cached, land in VGPRs) ----
    const floatx4* fArow = (const floatx4*)(features + (size_t)rAc * EMBED);
    const floatx4* fBrow = (const floatx4*)(features + (size_t)rBc * EMBED);
    floatx4 a0 = fArow[lane];
    floatx4 a1 = fArow[lane + 64];
    floatx4 a2 = fArow[lane + 128];
    floatx4 a3 = fArow[lane + 192];
    floatx4 b0 = fBrow[lane];
    floatx4 b1 = fBrow[lane + 64];
    floatx4 b2 = fBrow[lane + 128];
    floatx4 b3 = fBrow[lane + 192];

    __syncthreads();   // vmcnt(0) drain: staged labels + features complete

    // ---- label scan from LDS -> ballot -> class per row ----
    const floatx4* lAv = (const floatx4*)&s_lab[2 * wave][0];
    const floatx4* lBv = (const floatx4*)&s_lab[2 * wave + 1][0];

    int candA = -1, candB = -1;
    #define SCAN(CAND, V, IDX) { \
        floatx4 v_ = (V); int i_ = (IDX); \
        if (v_.x != 0.f || v_.y != 0.f || v_.z != 0.f || v_.w != 0.f) { \
            int c_ = 4 * i_; \
            if      (v_.y != 0.f) c_ += 1; \
            else if (v_.z != 0.f) c_ += 2; \
            else if (v_.w != 0.f) c_ += 3; \
            CAND = c_; \
        } }
    SCAN(candA, lAv[lane],        lane)
    SCAN(candA, lAv[lane + 64],   lane + 64)
    SCAN(candA, lAv[lane + 128],  lane + 128)
    if (lane < 58) SCAN(candA, lAv[lane + 192], lane + 192)
    SCAN(candB, lBv[lane],        lane)
    SCAN(candB, lBv[lane + 64],   lane + 64)
    SCAN(candB, lBv[lane + 128],  lane + 128)
    if (lane < 58) SCAN(candB, lBv[lane + 192], lane + 192)
    #undef SCAN

    unsigned long long mA = __ballot(candA >= 0);
    unsigned long long mB = __ballot(candB >= 0);
    int clsA = __shfl(candA, __ffsll(mA) - 1, 64);
    int clsB = __shfl(candB, __ffsll(mB) - 1, 64);
    clsA = __builtin_amdgcn_readfirstlane(clsA);
    clsB = __builtin_amdgcn_readfirstlane(clsB);

    // ---- prototype gather (cache-hot) + dots ----
    const floatx4* pArow = (const floatx4*)(mean_class + (size_t)clsA * EMBED);
    const floatx4* pBrow = (const floatx4*)(mean_class + (size_t)clsB * EMBED);
    floatx4 pa0 = pArow[lane];
    floatx4 pa1 = pArow[lane + 64];
    floatx4 pa2 = pArow[lane + 128];
    floatx4 pa3 = pArow[lane + 192];
    floatx4 pb0 = pBrow[lane];
    floatx4 pb1 = pBrow[lane + 64];
    floatx4 pb2 = pBrow[lane + 128];
    floatx4 pb3 = pBrow[lane + 192];

    float ffA = 0.f, ppA = 0.f, fpA = 0.f;
    float ffB = 0.f, ppB = 0.f, fpB = 0.f;
    #define DOT3(FF, PP, FP, F, P) \
        FF += F.x*F.x + F.y*F.y + F.z*F.z + F.w*F.w; \
        PP += P.x*P.x + P.y*P.y + P.z*P.z + P.w*P.w; \
        FP += F.x*P.x + F.y*P.y + F.z*P.z + F.w*P.w;
    DOT3(ffA, ppA, fpA, a0, pa0) DOT3(ffA, ppA, fpA, a1, pa1)
    DOT3(ffA, ppA, fpA, a2, pa2) DOT3(ffA, ppA, fpA, a3, pa3)
    DOT3(ffB, ppB, fpB, b0, pb0) DOT3(ffB, ppB, fpB, b1, pb1)
    DOT3(ffB, ppB, fpB, b2, pb2) DOT3(ffB, ppB, fpB, b3, pb3)
    #undef DOT3

    #pragma unroll
    for (int msk = 1; msk < 64; msk <<= 1) {
        ffA += __shfl_xor(ffA, msk, 64);
        ppA += __shfl_xor(ppA, msk, 64);
        fpA += __shfl_xor(fpA, msk, 64);
        ffB += __shfl_xor(ffB, msk, 64);
        ppB += __shfl_xor(ppB, msk, 64);
        fpB += __shfl_xor(fpB, msk, 64);
    }

    float res = 0.f;
    if (okA) res += 1.0f - fpA / (fmaxf(sqrtf(ffA), 1e-12f) * fmaxf(sqrtf(ppA), 1e-12f));
    if (okB) res += 1.0f - fpB / (fmaxf(sqrtf(ffB), 1e-12f) * fmaxf(sqrtf(ppB), 1e-12f));

    if (lane == 0) s_red[wave] = res;
    __syncthreads();
    if (tid == 0)
        partials[blockIdx.x] = s_red[0] + s_red[1] + s_red[2] + s_red[3];
}

__global__ __launch_bounds__(256) void reduce_partials_kernel(
    const float* __restrict__ partials, int num_partials,
    float* __restrict__ out, float inv_n)
{
    const int tid  = threadIdx.x;
    const int lane = tid & 63;
    const int wave = tid >> 6;
    __shared__ float s_red[4];

    float acc = 0.0f;
    for (int i = tid; i < num_partials; i += 256)
        acc += partials[i];
    #pragma unroll
    for (int msk = 1; msk < 64; msk <<= 1)
        acc += __shfl_xor(acc, msk, 64);
    if (lane == 0) s_red[wave] = acc;
    __syncthreads();
    if (tid == 0)
        out[0] = (s_red[0] + s_red[1] + s_red[2] + s_red[3]) * inv_n;
}

extern "C" void kernel_launch(void* const* d_in, const int* in_sizes, int n_in,
                              void* d_out, int out_size, void* d_ws, size_t ws_size,
                              hipStream_t stream) {
    const float* features   = (const float*)d_in[0];
    const float* labels     = (const float*)d_in[1];
    const float* mean_class = (const float*)d_in[2];
    float* out = (float*)d_out;
    float* partials = (float*)d_ws;

    const int n_rows = in_sizes[0] / EMBED;                                 // 32768
    const int num_blocks = (n_rows + ROWS_PER_BLOCK - 1) / ROWS_PER_BLOCK;  // 4096

    angular_fused_kernel<<<num_blocks, 256, 0, stream>>>(
        features, labels, mean_class, partials, n_rows);
    reduce_partials_kernel<<<1, 256, 0, stream>>>(
        partials, num_blocks, out, 1.0f / (float)n_rows);
}

// Round 8
// 255.101 us; speedup vs baseline: 1.1009x; 1.1009x over previous
//
#include <hip/hip_runtime.h>

constexpr int N_CLASSES = 1000;   // 250 float4 per label row
constexpr int EMBED     = 1024;   // 256 float4 per row; 4 float4 per lane

typedef float floatx4 __attribute__((ext_vector_type(4)));

__device__ __forceinline__ floatx4 ntload(const floatx4* p) {
    return __builtin_nontemporal_load(p);
}

// Persistent grid-stride, wave-per-row, 2-stage software pipeline:
// row r+stride's 8 streaming loads are issued BEFORE row r is consumed, so
// the consume point waits vmcnt(8) (not 0) and the stream never drains.
// nt on features/labels keeps the 4 MB mean_class set L2-resident.
__global__ __launch_bounds__(256, 4) void angular_pipelined_kernel(
    const float* __restrict__ features,
    const float* __restrict__ labels,
    const float* __restrict__ mean_class,
    float* __restrict__ partials,
    int n_rows)
{
    const int tid  = threadIdx.x;
    const int lane = tid & 63;
    const int wave = tid >> 6;
    const int wave_id = (blockIdx.x * blockDim.x + tid) >> 6;
    const int n_waves = (gridDim.x * blockDim.x) >> 6;

    float acc = 0.0f;

    int r = wave_id;
    floatx4 f0, f1, f2, f3, l0, l1, l2, l3;
    if (r < n_rows) {   // prologue: issue row r's loads
        const floatx4* frow = (const floatx4*)(features + (size_t)r * EMBED);
        f0 = ntload(frow + lane);       f1 = ntload(frow + lane + 64);
        f2 = ntload(frow + lane + 128); f3 = ntload(frow + lane + 192);
        const floatx4* lrow = (const floatx4*)(labels + (size_t)r * N_CLASSES);
        l0 = ntload(lrow + lane);       l1 = ntload(lrow + lane + 64);
        l2 = ntload(lrow + lane + 128);
        l3 = (lane < N_CLASSES / 4 - 192) ? ntload(lrow + lane + 192)
                                          : (floatx4){0.f, 0.f, 0.f, 0.f};
    }

    while (r < n_rows) {
        const int rn = r + n_waves;
        const bool has_next = rn < n_rows;          // wave-uniform
        floatx4 nf0, nf1, nf2, nf3, nl0, nl1, nl2, nl3;
        if (has_next) {   // issue next row's loads BEFORE consuming current
            const floatx4* frow = (const floatx4*)(features + (size_t)rn * EMBED);
            nf0 = ntload(frow + lane);       nf1 = ntload(frow + lane + 64);
            nf2 = ntload(frow + lane + 128); nf3 = ntload(frow + lane + 192);
            const floatx4* lrow = (const floatx4*)(labels + (size_t)rn * N_CLASSES);
            nl0 = ntload(lrow + lane);       nl1 = ntload(lrow + lane + 64);
            nl2 = ntload(lrow + lane + 128);
            nl3 = (lane < N_CLASSES / 4 - 192) ? ntload(lrow + lane + 192)
                                               : (floatx4){0.f, 0.f, 0.f, 0.f};
        }

        // ---- consume current row: one-hot scan -> ballot -> class ----
        int cand = -1;
        #define SCAN(V, IDX) { \
            if (V.x != 0.f || V.y != 0.f || V.z != 0.f || V.w != 0.f) { \
                int c_ = 4 * (IDX); \
                if      (V.y != 0.f) c_ += 1; \
                else if (V.z != 0.f) c_ += 2; \
                else if (V.w != 0.f) c_ += 3; \
                cand = c_; \
            } }
        SCAN(l0, lane) SCAN(l1, lane + 64) SCAN(l2, lane + 128) SCAN(l3, lane + 192)
        #undef SCAN

        unsigned long long m = __ballot(cand >= 0);
        int cls = __shfl(cand, __ffsll(m) - 1, 64);
        cls = __builtin_amdgcn_readfirstlane(cls);

        // ---- prototype gather (cached, L2-hot) + dots ----
        const floatx4* prow = (const floatx4*)(mean_class + (size_t)cls * EMBED);
        floatx4 p0 = prow[lane];
        floatx4 p1 = prow[lane + 64];
        floatx4 p2 = prow[lane + 128];
        floatx4 p3 = prow[lane + 192];

        float ff = 0.f, pp = 0.f, fp = 0.f;
        #define DOT3(F, P) \
            ff += F.x*F.x + F.y*F.y + F.z*F.z + F.w*F.w; \
            pp += P.x*P.x + P.y*P.y + P.z*P.z + P.w*P.w; \
            fp += F.x*P.x + F.y*P.y + F.z*P.z + F.w*P.w;
        DOT3(f0, p0) DOT3(f1, p1) DOT3(f2, p2) DOT3(f3, p3)
        #undef DOT3

        #pragma unroll
        for (int msk = 1; msk < 64; msk <<= 1) {
            ff += __shfl_xor(ff, msk, 64);
            pp += __shfl_xor(pp, msk, 64);
            fp += __shfl_xor(fp, msk, 64);
        }
        acc += 1.0f - fp / (fmaxf(sqrtf(ff), 1e-12f) * fmaxf(sqrtf(pp), 1e-12f));

        // ---- rotate pipeline ----
        r = rn;
        if (has_next) {
            f0 = nf0; f1 = nf1; f2 = nf2; f3 = nf3;
            l0 = nl0; l1 = nl1; l2 = nl2; l3 = nl3;
        }
    }

    __shared__ float s_red[4];
    if (lane == 0) s_red[wave] = acc;
    __syncthreads();
    if (tid == 0)
        partials[blockIdx.x] = s_red[0] + s_red[1] + s_red[2] + s_red[3];
}

__global__ __launch_bounds__(256) void reduce_partials_kernel(
    const float* __restrict__ partials, int num_partials,
    float* __restrict__ out, float inv_n)
{
    const int tid  = threadIdx.x;
    const int lane = tid & 63;
    const int wave = tid >> 6;
    __shared__ float s_red[4];

    float acc = 0.0f;
    for (int i = tid; i < num_partials; i += 256)
        acc += partials[i];
    #pragma unroll
    for (int msk = 1; msk < 64; msk <<= 1)
        acc += __shfl_xor(acc, msk, 64);
    if (lane == 0) s_red[wave] = acc;
    __syncthreads();
    if (tid == 0)
        out[0] = (s_red[0] + s_red[1] + s_red[2] + s_red[3]) * inv_n;
}

extern "C" void kernel_launch(void* const* d_in, const int* in_sizes, int n_in,
                              void* d_out, int out_size, void* d_ws, size_t ws_size,
                              hipStream_t stream) {
    const float* features   = (const float*)d_in[0];
    const float* labels     = (const float*)d_in[1];
    const float* mean_class = (const float*)d_in[2];
    float* out = (float*)d_out;
    float* partials = (float*)d_ws;

    const int n_rows = in_sizes[0] / EMBED;   // 32768
    const int num_blocks = 1024;              // 4096 persistent waves, 8 rows each

    angular_pipelined_kernel<<<num_blocks, 256, 0, stream>>>(
        features, labels, mean_class, partials, n_rows);
    reduce_partials_kernel<<<1, 256, 0, stream>>>(
        partials, num_blocks, out, 1.0f / (float)n_rows);
}